// Round 4
// baseline (154.517 us; speedup 1.0000x reference)
//
#include <hip/hip_runtime.h>

#define DEPTH 11
#define D 1024
#define H 32
#define OW 1024
#define B 4096
#define N_LEAVES 2048
#define N_NODES 2047
#define SMAX 4
#define MAX_ITEMS 3072

// ---------------------------------------------------------------------------
// Kernel 1: tree descent. One wave (64 lanes) per sample. x row held in 4
// float4 registers; per level gather node plane, f64 dot (match np f64 ref on
// the hard >=0 decision), butterfly shuffle-reduce, uniform node update.
// ---------------------------------------------------------------------------
__global__ __launch_bounds__(256) void descent_kernel(
    const float* __restrict__ x, const float* __restrict__ nw,
    const float* __restrict__ nb, int* __restrict__ leaf,
    int* __restrict__ rnk, int* __restrict__ count)
{
    int lane = threadIdx.x & 63;
    int wv   = threadIdx.x >> 6;
    int samp = blockIdx.x * 4 + wv;

    const float4* xp = (const float4*)(x + (size_t)samp * D);
    float4 xf[4];
#pragma unroll
    for (int k = 0; k < 4; k++) xf[k] = xp[lane + 64 * k];

    int node = 0;
#pragma unroll
    for (int i = 0; i < DEPTH; i++) {
        const float4* wp = (const float4*)(nw + (size_t)node * D);
        double s = 0.0;
#pragma unroll
        for (int k = 0; k < 4; k++) {
            float4 wf = wp[lane + 64 * k];
            s += (double)xf[k].x * (double)wf.x;
            s += (double)xf[k].y * (double)wf.y;
            s += (double)xf[k].z * (double)wf.z;
            s += (double)xf[k].w * (double)wf.w;
        }
#pragma unroll
        for (int m = 32; m >= 1; m >>= 1) s += __shfl_xor(s, m, 64);
        double score = s + (double)nb[node];
        int choice = (score >= 0.0) ? 1 : 0;
        node = 2 * node + 1 + choice;
    }
    int lf = node - N_NODES;
    if (lane == 0) {
        leaf[samp] = lf;
        rnk[samp]  = atomicAdd(&count[lf], 1);
    }
}

// ---------------------------------------------------------------------------
// Kernel 2: exclusive prefix scan over 2048 leaf counts. Single block.
// ---------------------------------------------------------------------------
__global__ __launch_bounds__(256) void scan_kernel(
    const int* __restrict__ count, int* __restrict__ offsets)
{
    __shared__ int tot[256];
    int t = threadIdx.x;
    int c[8], s = 0;
#pragma unroll
    for (int k = 0; k < 8; k++) { c[k] = count[t * 8 + k]; s += c[k]; }
    tot[t] = s;
    __syncthreads();
    for (int off = 1; off < 256; off <<= 1) {
        int v = (t >= off) ? tot[t - off] : 0;
        __syncthreads();
        tot[t] += v;
        __syncthreads();
    }
    int base = (t > 0) ? tot[t - 1] : 0;
#pragma unroll
    for (int k = 0; k < 8; k++) { offsets[t * 8 + k] = base; base += c[k]; }
}

// ---------------------------------------------------------------------------
// Kernel 3: scatter sample ids into per-leaf buckets.
// ---------------------------------------------------------------------------
__global__ __launch_bounds__(256) void scatter_kernel(
    const int* __restrict__ leaf, const int* __restrict__ rnk,
    const int* __restrict__ offsets, int* __restrict__ bucket)
{
    int i = blockIdx.x * 256 + threadIdx.x;
    bucket[offsets[leaf[i]] + rnk[i]] = i;
}

// ---------------------------------------------------------------------------
// Kernel 3b: build work items of <=SMAX samples each. Heavy leaves become
// multiple parallel items (kills the serial second-pass tail).
// item = leaf | (start << 11).
// ---------------------------------------------------------------------------
__global__ __launch_bounds__(256) void build_items_kernel(
    const int* __restrict__ count, int* __restrict__ items,
    int* __restrict__ nitems)
{
    int l = blockIdx.x * 256 + threadIdx.x;
    int c = count[l];
    if (c > 0) {
        int k = (c + SMAX - 1) / SMAX;
        int base = atomicAdd(nitems, k);
        for (int i = 0; i < k; i++)
            items[base + i] = l | ((i * SMAX) << 11);
    }
}

// ---------------------------------------------------------------------------
// Kernel 4: per-leaf-item MLP. Explicit 8-deep float4 staging in both layers
// so ~8 KB/wave stays in flight (Little's law: the round-3 VGPR=32 build had
// ~2 loads in flight -> 1.7 TB/s). launch_bounds(256,6): VGPR cap 85, LDS
// (19.5 KB) still allows up to 8 blocks/CU if compiler stays <=64 VGPR.
// ---------------------------------------------------------------------------
template <int SS>
__device__ __forceinline__ void mlp_compute(
    int tid, const float* __restrict__ w1, const float* __restrict__ w2,
    const float* __restrict__ b1, const float* __restrict__ b2,
    float (*xs)[D], float (*pl1)[32][SMAX], float (*hs)[H],
    const int* sidx, float* __restrict__ out)
{
    const int lane = tid & 63, wave = tid >> 6;
    const int jq = tid & 7, dg = tid >> 3;
    const float4* w1v = (const float4*)w1;

    float4 acc[SS];
#pragma unroll
    for (int s = 0; s < SS; s++) acc[s] = make_float4(0.f, 0.f, 0.f, 0.f);

    // ---- layer 1: 32 rows per thread in 4 batches of 8 staged loads ----
#pragma unroll
    for (int kk = 0; kk < 32; kk += 8) {
        float4 w[8];
#pragma unroll
        for (int u = 0; u < 8; u++)
            w[u] = w1v[((dg + ((kk + u) << 5)) << 3) + jq];
#pragma unroll
        for (int u = 0; u < 8; u++) {
            int d = dg + ((kk + u) << 5);
#pragma unroll
            for (int s = 0; s < SS; s++) {
                float xv = xs[s][d];
                acc[s].x += xv * w[u].x;
                acc[s].y += xv * w[u].y;
                acc[s].z += xv * w[u].z;
                acc[s].w += xv * w[u].w;
            }
        }
    }
    // reduce across the 8 dg's within this wave (tid bits 3..5)
#pragma unroll
    for (int m = 8; m <= 32; m <<= 1)
#pragma unroll
        for (int s = 0; s < SS; s++) {
            acc[s].x += __shfl_xor(acc[s].x, m, 64);
            acc[s].y += __shfl_xor(acc[s].y, m, 64);
            acc[s].z += __shfl_xor(acc[s].z, m, 64);
            acc[s].w += __shfl_xor(acc[s].w, m, 64);
        }
    if (lane < 8) {
#pragma unroll
        for (int s = 0; s < SS; s++) {
            pl1[wave][jq * 4 + 0][s] = acc[s].x;
            pl1[wave][jq * 4 + 1][s] = acc[s].y;
            pl1[wave][jq * 4 + 2][s] = acc[s].z;
            pl1[wave][jq * 4 + 3][s] = acc[s].w;
        }
    }
    __syncthreads();
    if (tid < 32 * SS) {
        int s2 = tid >> 5, j2 = tid & 31;
        float sum = pl1[0][j2][s2] + pl1[1][j2][s2] + pl1[2][j2][s2] +
                    pl1[3][j2][s2] + b1[j2];
        hs[s2][j2] = fmaxf(sum, 0.f);
    }
    __syncthreads();

    // ---- layer 2: 32 rows of w2 in 4 batches of 8 staged loads ----
    const float4* w2v = (const float4*)w2;
    float4 o[SS];
#pragma unroll
    for (int s = 0; s < SS; s++) o[s] = make_float4(0.f, 0.f, 0.f, 0.f);
#pragma unroll
    for (int j0 = 0; j0 < H; j0 += 8) {
        float4 w[8];
#pragma unroll
        for (int u = 0; u < 8; u++)
            w[u] = w2v[((j0 + u) << 8) + tid];
#pragma unroll
        for (int u = 0; u < 8; u++)
#pragma unroll
            for (int s = 0; s < SS; s++) {
                float hv = hs[s][j0 + u];
                o[s].x += hv * w[u].x;
                o[s].y += hv * w[u].y;
                o[s].z += hv * w[u].z;
                o[s].w += hv * w[u].w;
            }
    }
    float4 bv = ((const float4*)b2)[tid];
#pragma unroll
    for (int s = 0; s < SS; s++) {
        float4 o4;
        o4.x = o[s].x + bv.x;
        o4.y = o[s].y + bv.y;
        o4.z = o[s].z + bv.z;
        o4.w = o[s].w + bv.w;
        ((float4*)(out + (size_t)sidx[s] * OW))[tid] = o4;
    }
}

__global__ __launch_bounds__(256, 6) void mlp_kernel(
    const float* __restrict__ x, const float* __restrict__ w1s,
    const float* __restrict__ b1s, const float* __restrict__ w2s,
    const float* __restrict__ b2s, const int* __restrict__ offsets,
    const int* __restrict__ count, const int* __restrict__ bucket,
    const int* __restrict__ items, const int* __restrict__ nitems,
    float* __restrict__ out)
{
    __shared__ float xs[SMAX][D];          // 16 KB
    __shared__ float pl1[4][32][SMAX];     // 2 KB
    __shared__ float hs[SMAX][H];          // 0.5 KB
    __shared__ int   sidx[SMAX];

    if ((int)blockIdx.x >= nitems[0]) return;
    int item  = items[blockIdx.x];
    int l     = item & (N_LEAVES - 1);
    int start = item >> 11;
    int S     = min(SMAX, count[l] - start);
    int base  = offsets[l] + start;
    int tid   = threadIdx.x;

    const float* w1 = w1s + (size_t)l * D * H;
    const float* w2 = w2s + (size_t)l * H * OW;
    const float* b1 = b1s + (size_t)l * H;
    const float* b2 = b2s + (size_t)l * OW;

    if (tid < S) sidx[tid] = bucket[base + tid];
    __syncthreads();
    for (int s = 0; s < S; s++) {
        ((float4*)xs[s])[tid] = ((const float4*)(x + (size_t)sidx[s] * D))[tid];
    }
    __syncthreads();
    switch (S) {
        case 1: mlp_compute<1>(tid, w1, w2, b1, b2, xs, pl1, hs, sidx, out); break;
        case 2: mlp_compute<2>(tid, w1, w2, b1, b2, xs, pl1, hs, sidx, out); break;
        case 3: mlp_compute<3>(tid, w1, w2, b1, b2, xs, pl1, hs, sidx, out); break;
        default: mlp_compute<4>(tid, w1, w2, b1, b2, xs, pl1, hs, sidx, out); break;
    }
}

// ---------------------------------------------------------------------------
extern "C" void kernel_launch(void* const* d_in, const int* in_sizes, int n_in,
                              void* d_out, int out_size, void* d_ws, size_t ws_size,
                              hipStream_t stream)
{
    const float* x   = (const float*)d_in[0];
    const float* nw  = (const float*)d_in[1];
    const float* nb  = (const float*)d_in[2];
    const float* w1s = (const float*)d_in[3];
    const float* b1s = (const float*)d_in[4];
    const float* w2s = (const float*)d_in[5];
    const float* b2s = (const float*)d_in[6];
    float* out = (float*)d_out;

    int* leaf    = (int*)d_ws;
    int* rnk     = leaf + B;
    int* count   = rnk + B;
    int* offsets = count + N_LEAVES;
    int* bucket  = offsets + N_LEAVES;
    int* items   = bucket + B;
    int* nitems  = items + MAX_ITEMS;

    hipMemsetAsync(count, 0, N_LEAVES * sizeof(int), stream);
    hipMemsetAsync(nitems, 0, sizeof(int), stream);
    descent_kernel<<<B / 4, 256, 0, stream>>>(x, nw, nb, leaf, rnk, count);
    scan_kernel<<<1, 256, 0, stream>>>(count, offsets);
    scatter_kernel<<<B / 256, 256, 0, stream>>>(leaf, rnk, offsets, bucket);
    build_items_kernel<<<N_LEAVES / 256, 256, 0, stream>>>(count, items, nitems);
    mlp_kernel<<<MAX_ITEMS, 256, 0, stream>>>(x, w1s, b1s, w2s, b2s,
                                              offsets, count, bucket,
                                              items, nitems, out);
}

// Round 5
// 131.849 us; speedup vs baseline: 1.1719x; 1.1719x over previous
//
#include <hip/hip_runtime.h>

#define DEPTH 11
#define D 1024
#define H 32
#define OW 1024
#define B 4096
#define N_LEAVES 2048
#define N_NODES 2047
#define SMAX 4
#define MAX_ITEMS 3072
#define CHUNKF 4096   // floats per 16 KB chunk

typedef __attribute__((address_space(3))) void lds_void;
typedef const __attribute__((address_space(1))) void glb_void;

// ---------------------------------------------------------------------------
// Kernel 1: tree descent. One wave per sample; f64 dot to match the np f64
// reference on the hard >=0 branch decision.
// ---------------------------------------------------------------------------
__global__ __launch_bounds__(256) void descent_kernel(
    const float* __restrict__ x, const float* __restrict__ nw,
    const float* __restrict__ nb, int* __restrict__ leaf,
    int* __restrict__ rnk, int* __restrict__ count)
{
    int lane = threadIdx.x & 63;
    int wv   = threadIdx.x >> 6;
    int samp = blockIdx.x * 4 + wv;

    const float4* xp = (const float4*)(x + (size_t)samp * D);
    float4 xf[4];
#pragma unroll
    for (int k = 0; k < 4; k++) xf[k] = xp[lane + 64 * k];

    int node = 0;
#pragma unroll
    for (int i = 0; i < DEPTH; i++) {
        const float4* wp = (const float4*)(nw + (size_t)node * D);
        double s = 0.0;
#pragma unroll
        for (int k = 0; k < 4; k++) {
            float4 wf = wp[lane + 64 * k];
            s += (double)xf[k].x * (double)wf.x;
            s += (double)xf[k].y * (double)wf.y;
            s += (double)xf[k].z * (double)wf.z;
            s += (double)xf[k].w * (double)wf.w;
        }
#pragma unroll
        for (int m = 32; m >= 1; m >>= 1) s += __shfl_xor(s, m, 64);
        double score = s + (double)nb[node];
        int choice = (score >= 0.0) ? 1 : 0;
        node = 2 * node + 1 + choice;
    }
    int lf = node - N_NODES;
    if (lane == 0) {
        leaf[samp] = lf;
        rnk[samp]  = atomicAdd(&count[lf], 1);
    }
}

// ---------------------------------------------------------------------------
// Kernel 2: exclusive prefix scan over 2048 leaf counts. Single block.
// ---------------------------------------------------------------------------
__global__ __launch_bounds__(256) void scan_kernel(
    const int* __restrict__ count, int* __restrict__ offsets)
{
    __shared__ int tot[256];
    int t = threadIdx.x;
    int c[8], s = 0;
#pragma unroll
    for (int k = 0; k < 8; k++) { c[k] = count[t * 8 + k]; s += c[k]; }
    tot[t] = s;
    __syncthreads();
    for (int off = 1; off < 256; off <<= 1) {
        int v = (t >= off) ? tot[t - off] : 0;
        __syncthreads();
        tot[t] += v;
        __syncthreads();
    }
    int base = (t > 0) ? tot[t - 1] : 0;
#pragma unroll
    for (int k = 0; k < 8; k++) { offsets[t * 8 + k] = base; base += c[k]; }
}

// ---------------------------------------------------------------------------
// Kernel 3: scatter sample ids into per-leaf buckets.
// ---------------------------------------------------------------------------
__global__ __launch_bounds__(256) void scatter_kernel(
    const int* __restrict__ leaf, const int* __restrict__ rnk,
    const int* __restrict__ offsets, int* __restrict__ bucket)
{
    int i = blockIdx.x * 256 + threadIdx.x;
    bucket[offsets[leaf[i]] + rnk[i]] = i;
}

// ---------------------------------------------------------------------------
// Kernel 3b: build work items of <=SMAX samples (heavy leaves -> parallel
// items, no serial second pass). item = leaf | (start << 11).
// ---------------------------------------------------------------------------
__global__ __launch_bounds__(256) void build_items_kernel(
    const int* __restrict__ count, int* __restrict__ items,
    int* __restrict__ nitems)
{
    int l = blockIdx.x * 256 + threadIdx.x;
    int c = count[l];
    if (c > 0) {
        int k = (c + SMAX - 1) / SMAX;
        int base = atomicAdd(nitems, k);
        for (int i = 0; i < k; i++)
            items[base + i] = l | ((i * SMAX) << 11);
    }
}

// ---------------------------------------------------------------------------
// Async 16 KB chunk stage: 4 global_load_lds_dwordx4 per wave (1 KB each).
// LDS dest is wave-uniform base (HW adds lane*16); source is per-lane.
// Linear layout both sides (rule #21: no swizzle on either side).
// ---------------------------------------------------------------------------
__device__ __forceinline__ void stage16k(const float* __restrict__ src,
                                         float* ldsbase, int wave, int lane)
{
#pragma unroll
    for (int i = 0; i < 4; i++) {
        const float* g = src + wave * 1024 + i * 256 + lane * 4;
        float*       l = ldsbase + wave * 1024 + i * 256;  // wave-uniform
        __builtin_amdgcn_global_load_lds((glb_void*)g, (lds_void*)l, 16, 0, 0);
    }
}

// ---------------------------------------------------------------------------
// Kernel 4: per-item MLP with DMA-pipelined weights (m97 2-phase structure):
// stage chunk c+1 ∥ compute chunk c from LDS; one __syncthreads per chunk
// (its vmcnt(0)-drain is the chunk-arrival wait). Weights never touch VGPRs.
// ---------------------------------------------------------------------------
template <int SS>
__device__ __forceinline__ void mlp_item(
    int tid, const float* __restrict__ x, const float* __restrict__ w1,
    const float* __restrict__ w2, const float* __restrict__ b1,
    const float* __restrict__ b2, const int* __restrict__ bucket, int base,
    float (*xs)[D], float* wbuf, float (*pl1)[32][SMAX], float (*hs)[H],
    float* __restrict__ out)
{
    const int lane = tid & 63, wave = tid >> 6;
    const int jq = tid & 7, dg = tid >> 3;

    int sid[SS];
#pragma unroll
    for (int s = 0; s < SS; s++) sid[s] = bucket[base + s];

    // async stage: x rows + w1 chunk 0
#pragma unroll
    for (int s = 0; s < SS; s++) {
        const float* g = x + (size_t)sid[s] * D + wave * 256 + lane * 4;
        float*       l = xs[s] + wave * 256;
        __builtin_amdgcn_global_load_lds((glb_void*)g, (lds_void*)l, 16, 0, 0);
    }
    stage16k(w1, wbuf, wave, lane);
    __syncthreads();

    // ---- layer 1: 8 chunks of 128 rows; thread (dg,jq) does 4 rows/chunk ----
    float4 acc[SS];
#pragma unroll
    for (int s = 0; s < SS; s++) acc[s] = make_float4(0.f, 0.f, 0.f, 0.f);

    for (int c = 0; c < 8; c++) {
        const float* nsrc = (c < 7) ? (w1 + (c + 1) * CHUNKF) : w2;
        stage16k(nsrc, wbuf + ((c + 1) & 1) * CHUNKF, wave, lane);
        const float* wb = wbuf + (c & 1) * CHUNKF;
        int d0 = c * 128;
#pragma unroll
        for (int k = 0; k < 4; k++) {
            int r = dg + (k << 5);
            float4 w = *(const float4*)(wb + r * 32 + jq * 4);
#pragma unroll
            for (int s = 0; s < SS; s++) {
                float xv = xs[s][d0 + r];
                acc[s].x += xv * w.x;
                acc[s].y += xv * w.y;
                acc[s].z += xv * w.z;
                acc[s].w += xv * w.w;
            }
        }
        __syncthreads();
    }

    // ---- reduce: shfl over dg bits 0..2 (lane bits 3..5), then LDS over waves
#pragma unroll
    for (int m = 8; m <= 32; m <<= 1)
#pragma unroll
        for (int s = 0; s < SS; s++) {
            acc[s].x += __shfl_xor(acc[s].x, m, 64);
            acc[s].y += __shfl_xor(acc[s].y, m, 64);
            acc[s].z += __shfl_xor(acc[s].z, m, 64);
            acc[s].w += __shfl_xor(acc[s].w, m, 64);
        }
    if (lane < 8) {
#pragma unroll
        for (int s = 0; s < SS; s++) {
            pl1[wave][jq * 4 + 0][s] = acc[s].x;
            pl1[wave][jq * 4 + 1][s] = acc[s].y;
            pl1[wave][jq * 4 + 2][s] = acc[s].z;
            pl1[wave][jq * 4 + 3][s] = acc[s].w;
        }
    }
    __syncthreads();
    if (tid < 32 * SS) {
        int s2 = tid >> 5, j2 = tid & 31;
        float sum = pl1[0][j2][s2] + pl1[1][j2][s2] + pl1[2][j2][s2] +
                    pl1[3][j2][s2] + b1[j2];
        hs[s2][j2] = fmaxf(sum, 0.f);
    }
    __syncthreads();

    // ---- layer 2: 8 chunks of 4 w2-rows; thread owns cols 4*tid..4*tid+3 ----
    float4 o[SS];
#pragma unroll
    for (int s = 0; s < SS; s++) o[s] = make_float4(0.f, 0.f, 0.f, 0.f);

    for (int c = 0; c < 8; c++) {
        if (c < 7)
            stage16k(w2 + (c + 1) * CHUNKF, wbuf + ((c + 1) & 1) * CHUNKF, wave, lane);
        const float* wb = wbuf + (c & 1) * CHUNKF;
        int j0 = c * 4;
#pragma unroll
        for (int jj = 0; jj < 4; jj++) {
            float4 w = *(const float4*)(wb + jj * 1024 + tid * 4);
#pragma unroll
            for (int s = 0; s < SS; s++) {
                float hv = hs[s][j0 + jj];
                o[s].x += hv * w.x;
                o[s].y += hv * w.y;
                o[s].z += hv * w.z;
                o[s].w += hv * w.w;
            }
        }
        __syncthreads();
    }

    float4 bv = ((const float4*)b2)[tid];
#pragma unroll
    for (int s = 0; s < SS; s++) {
        float4 o4;
        o4.x = o[s].x + bv.x;
        o4.y = o[s].y + bv.y;
        o4.z = o[s].z + bv.z;
        o4.w = o[s].w + bv.w;
        ((float4*)(out + (size_t)sid[s] * OW))[tid] = o4;
    }
}

__global__ __launch_bounds__(256) void mlp_kernel(
    const float* __restrict__ x, const float* __restrict__ w1s,
    const float* __restrict__ b1s, const float* __restrict__ w2s,
    const float* __restrict__ b2s, const int* __restrict__ offsets,
    const int* __restrict__ count, const int* __restrict__ bucket,
    const int* __restrict__ items, const int* __restrict__ nitems,
    float* __restrict__ out)
{
    __shared__ float xs[SMAX][D];        // 16 KB
    __shared__ float wbuf[2][CHUNKF];    // 32 KB
    __shared__ float pl1[4][32][SMAX];   // 2 KB
    __shared__ float hs[SMAX][H];        // 0.5 KB

    if ((int)blockIdx.x >= nitems[0]) return;
    int item  = items[blockIdx.x];
    int l     = item & (N_LEAVES - 1);
    int start = item >> 11;
    int S     = min(SMAX, count[l] - start);
    int base  = offsets[l] + start;
    int tid   = threadIdx.x;

    const float* w1 = w1s + (size_t)l * D * H;
    const float* w2 = w2s + (size_t)l * H * OW;
    const float* b1 = b1s + (size_t)l * H;
    const float* b2 = b2s + (size_t)l * OW;

    switch (S) {
        case 1: mlp_item<1>(tid, x, w1, w2, b1, b2, bucket, base, xs, &wbuf[0][0], pl1, hs, out); break;
        case 2: mlp_item<2>(tid, x, w1, w2, b1, b2, bucket, base, xs, &wbuf[0][0], pl1, hs, out); break;
        case 3: mlp_item<3>(tid, x, w1, w2, b1, b2, bucket, base, xs, &wbuf[0][0], pl1, hs, out); break;
        default: mlp_item<4>(tid, x, w1, w2, b1, b2, bucket, base, xs, &wbuf[0][0], pl1, hs, out); break;
    }
}

// ---------------------------------------------------------------------------
extern "C" void kernel_launch(void* const* d_in, const int* in_sizes, int n_in,
                              void* d_out, int out_size, void* d_ws, size_t ws_size,
                              hipStream_t stream)
{
    const float* x   = (const float*)d_in[0];
    const float* nw  = (const float*)d_in[1];
    const float* nb  = (const float*)d_in[2];
    const float* w1s = (const float*)d_in[3];
    const float* b1s = (const float*)d_in[4];
    const float* w2s = (const float*)d_in[5];
    const float* b2s = (const float*)d_in[6];
    float* out = (float*)d_out;

    int* leaf    = (int*)d_ws;
    int* rnk     = leaf + B;
    int* count   = rnk + B;
    int* offsets = count + N_LEAVES;
    int* bucket  = offsets + N_LEAVES;
    int* items   = bucket + B;
    int* nitems  = items + MAX_ITEMS;

    hipMemsetAsync(count, 0, N_LEAVES * sizeof(int), stream);
    hipMemsetAsync(nitems, 0, sizeof(int), stream);
    descent_kernel<<<B / 4, 256, 0, stream>>>(x, nw, nb, leaf, rnk, count);
    scan_kernel<<<1, 256, 0, stream>>>(count, offsets);
    scatter_kernel<<<B / 256, 256, 0, stream>>>(leaf, rnk, offsets, bucket);
    build_items_kernel<<<N_LEAVES / 256, 256, 0, stream>>>(count, items, nitems);
    mlp_kernel<<<MAX_ITEMS, 256, 0, stream>>>(x, w1s, b1s, w2s, b2s,
                                              offsets, count, bucket,
                                              items, nitems, out);
}

// Round 6
// 125.928 us; speedup vs baseline: 1.2270x; 1.0470x over previous
//
#include <hip/hip_runtime.h>

#define DEPTH 11
#define D 1024
#define H 32
#define OW 1024
#define B 4096
#define N_LEAVES 2048
#define N_NODES 2047
#define SMAX 4
#define MAX_ITEMS 3072

typedef __attribute__((address_space(3))) void lds_void;
typedef const __attribute__((address_space(1))) void glb_void;

// counted waits (T4): never drain vmcnt mid-pipeline. sched_barrier stops the
// scheduler hoisting the dependent ds_reads above the wait (rule #18).
#define WAITV8  do { asm volatile("s_waitcnt vmcnt(8)" ::: "memory"); __builtin_amdgcn_sched_barrier(0); } while (0)
#define WAITV4  do { asm volatile("s_waitcnt vmcnt(4)" ::: "memory"); __builtin_amdgcn_sched_barrier(0); } while (0)
#define WAITV0  do { asm volatile("s_waitcnt vmcnt(0)" ::: "memory"); __builtin_amdgcn_sched_barrier(0); } while (0)
#define WAITLG0 do { asm volatile("s_waitcnt lgkmcnt(0)" ::: "memory"); __builtin_amdgcn_sched_barrier(0); } while (0)

// ---------------------------------------------------------------------------
// Kernel 1: tree descent. One wave per sample; f64 dot to match the np f64
// reference on the hard >=0 branch decision.
// ---------------------------------------------------------------------------
__global__ __launch_bounds__(256) void descent_kernel(
    const float* __restrict__ x, const float* __restrict__ nw,
    const float* __restrict__ nb, int* __restrict__ leaf,
    int* __restrict__ rnk, int* __restrict__ count)
{
    int lane = threadIdx.x & 63;
    int wv   = threadIdx.x >> 6;
    int samp = blockIdx.x * 4 + wv;

    const float4* xp = (const float4*)(x + (size_t)samp * D);
    float4 xf[4];
#pragma unroll
    for (int k = 0; k < 4; k++) xf[k] = xp[lane + 64 * k];

    int node = 0;
#pragma unroll
    for (int i = 0; i < DEPTH; i++) {
        const float4* wp = (const float4*)(nw + (size_t)node * D);
        double s = 0.0;
#pragma unroll
        for (int k = 0; k < 4; k++) {
            float4 wf = wp[lane + 64 * k];
            s += (double)xf[k].x * (double)wf.x;
            s += (double)xf[k].y * (double)wf.y;
            s += (double)xf[k].z * (double)wf.z;
            s += (double)xf[k].w * (double)wf.w;
        }
#pragma unroll
        for (int m = 32; m >= 1; m >>= 1) s += __shfl_xor(s, m, 64);
        double score = s + (double)nb[node];
        int choice = (score >= 0.0) ? 1 : 0;
        node = 2 * node + 1 + choice;
    }
    int lf = node - N_NODES;
    if (lane == 0) {
        leaf[samp] = lf;
        rnk[samp]  = atomicAdd(&count[lf], 1);
    }
}

// ---------------------------------------------------------------------------
// Kernel 2: exclusive prefix scan over 2048 leaf counts. Single block.
// ---------------------------------------------------------------------------
__global__ __launch_bounds__(256) void scan_kernel(
    const int* __restrict__ count, int* __restrict__ offsets)
{
    __shared__ int tot[256];
    int t = threadIdx.x;
    int c[8], s = 0;
#pragma unroll
    for (int k = 0; k < 8; k++) { c[k] = count[t * 8 + k]; s += c[k]; }
    tot[t] = s;
    __syncthreads();
    for (int off = 1; off < 256; off <<= 1) {
        int v = (t >= off) ? tot[t - off] : 0;
        __syncthreads();
        tot[t] += v;
        __syncthreads();
    }
    int base = (t > 0) ? tot[t - 1] : 0;
#pragma unroll
    for (int k = 0; k < 8; k++) { offsets[t * 8 + k] = base; base += c[k]; }
}

// ---------------------------------------------------------------------------
// Kernel 3: scatter sample ids into per-leaf buckets.
// ---------------------------------------------------------------------------
__global__ __launch_bounds__(256) void scatter_kernel(
    const int* __restrict__ leaf, const int* __restrict__ rnk,
    const int* __restrict__ offsets, int* __restrict__ bucket)
{
    int i = blockIdx.x * 256 + threadIdx.x;
    bucket[offsets[leaf[i]] + rnk[i]] = i;
}

// ---------------------------------------------------------------------------
// Kernel 3b: build work items of <=SMAX samples. item = leaf | (start << 11).
// ---------------------------------------------------------------------------
__global__ __launch_bounds__(256) void build_items_kernel(
    const int* __restrict__ count, int* __restrict__ items,
    int* __restrict__ nitems)
{
    int l = blockIdx.x * 256 + threadIdx.x;
    int c = count[l];
    if (c > 0) {
        int k = (c + SMAX - 1) / SMAX;
        int base = atomicAdd(nitems, k);
        for (int i = 0; i < k; i++)
            items[base + i] = l | ((i * SMAX) << 11);
    }
}

// ---------------------------------------------------------------------------
// Per-wave async stage of a 4 KB chunk (4 x 1 KB global_load_lds_dwordx4).
// dst must be wave-uniform; src is lane-contiguous.
// ---------------------------------------------------------------------------
__device__ __forceinline__ void stage4k(const float* src, float* dst, int lane)
{
#pragma unroll
    for (int i = 0; i < 4; i++)
        __builtin_amdgcn_global_load_lds((glb_void*)(src + i * 256 + lane * 4),
                                         (lds_void*)(dst + i * 256), 16, 0, 0);
}

// L2 chunk: 4 j-rows, this wave's 256-col slice (1 KB per j, strided in glb).
__device__ __forceinline__ void stageL2(const float* w2w, int cj, float* dst, int lane)
{
#pragma unroll
    for (int jl = 0; jl < 4; jl++)
        __builtin_amdgcn_global_load_lds(
            (glb_void*)(w2w + (size_t)(cj * 4 + jl) * OW + lane * 4),
            (lds_void*)(dst + jl * 256), 16, 0, 0);
}

// layer-1 chunk compute: 32 rows from LDS buffer p (linear: row r=u*8+dg).
template <int SS>
__device__ __forceinline__ void l1c(const float* p, const float* xsw, int c,
                                    int lane, int dg, float4* acc)
{
#pragma unroll
    for (int u = 0; u < 4; u++) {
        float4 w = ((const float4*)p)[u * 64 + lane];
#pragma unroll
        for (int s = 0; s < SS; s++) {
            float xv = xsw[s * D + c * 32 + u * 8 + dg];
            acc[s].x += xv * w.x;
            acc[s].y += xv * w.y;
            acc[s].z += xv * w.z;
            acc[s].w += xv * w.w;
        }
    }
}

// layer-2 chunk compute: 4 j's; lane owns 4 o-cols of the wave's 256-slice.
template <int SS>
__device__ __forceinline__ void l2c(const float* p, const float (*hs)[H], int cj,
                                    int lane, float4* o)
{
#pragma unroll
    for (int jl = 0; jl < 4; jl++) {
        float4 w = ((const float4*)p)[jl * 64 + lane];
#pragma unroll
        for (int s = 0; s < SS; s++) {
            float hv = hs[s][cj * 4 + jl];
            o[s].x += hv * w.x;
            o[s].y += hv * w.y;
            o[s].z += hv * w.z;
            o[s].w += hv * w.w;
        }
    }
}

// ---------------------------------------------------------------------------
// Kernel 4: per-item MLP. All staging is wave-private (wave w owns d-rows
// [w*256,(w+1)*256) in L1 and o-cols [w*256,(w+1)*256) in L2), so the only
// block syncs are two raw s_barriers (lgkmcnt only) around the h-reduce.
// Each wave: 8-chunk x 4 KB, 3-buffer pipeline, waits vmcnt(8)->4->0.
// ---------------------------------------------------------------------------
template <int SS>
__device__ __forceinline__ void mlp_item(
    int tid, const float* __restrict__ x, const float* __restrict__ w1,
    const float* __restrict__ w2, const float* __restrict__ b1,
    const float* __restrict__ b2, const int* __restrict__ bucket, int base,
    float* xs, float* wq, float (*pl1)[SMAX][32], float (*hs)[H],
    float* __restrict__ out)
{
    const int lane = tid & 63, wave = tid >> 6;
    const int jq = lane & 7, dg = lane >> 3;

    // bias preload; dummy-use pins the compiler's wait here (before DMAs).
    float b1v = b1[tid & 31];
    asm volatile("" :: "v"(b1v));

    int sid[SS];
#pragma unroll
    for (int s = 0; s < SS; s++) sid[s] = bucket[base + s];

    // prologue: x quarter + w1 chunks 0..2
#pragma unroll
    for (int s = 0; s < SS; s++)
        __builtin_amdgcn_global_load_lds(
            (glb_void*)(x + (size_t)sid[s] * D + wave * 256 + lane * 4),
            (lds_void*)(xs + s * D + wave * 256), 16, 0, 0);

    const float* w1w = w1 + wave * 8192;   // wave's 256 rows x 32 cols
    const float* xsw = xs + wave * 256;
    stage4k(w1w + 0 * 1024, wq + 0 * 1024, lane);
    stage4k(w1w + 1 * 1024, wq + 1 * 1024, lane);
    stage4k(w1w + 2 * 1024, wq + 2 * 1024, lane);

    float4 acc[SS];
#pragma unroll
    for (int s = 0; s < SS; s++) acc[s] = make_float4(0.f, 0.f, 0.f, 0.f);

    // ---- layer 1 pipeline: wait(c) -> compute(c) -> stage(c+3) ----
    WAITV8; l1c<SS>(wq + 0 * 1024, xsw, 0, lane, dg, acc); stage4k(w1w + 3 * 1024, wq + 0 * 1024, lane);
    WAITV8; l1c<SS>(wq + 1 * 1024, xsw, 1, lane, dg, acc); stage4k(w1w + 4 * 1024, wq + 1 * 1024, lane);
    WAITV8; l1c<SS>(wq + 2 * 1024, xsw, 2, lane, dg, acc); stage4k(w1w + 5 * 1024, wq + 2 * 1024, lane);
    WAITV8; l1c<SS>(wq + 0 * 1024, xsw, 3, lane, dg, acc); stage4k(w1w + 6 * 1024, wq + 0 * 1024, lane);
    WAITV8; l1c<SS>(wq + 1 * 1024, xsw, 4, lane, dg, acc); stage4k(w1w + 7 * 1024, wq + 1 * 1024, lane);
    WAITV8; l1c<SS>(wq + 2 * 1024, xsw, 5, lane, dg, acc);
    WAITV4; l1c<SS>(wq + 0 * 1024, xsw, 6, lane, dg, acc);
    WAITV0; l1c<SS>(wq + 1 * 1024, xsw, 7, lane, dg, acc);

    // reduce over dg (lane bits 3..5) within the wave
#pragma unroll
    for (int m = 8; m <= 32; m <<= 1)
#pragma unroll
        for (int s = 0; s < SS; s++) {
            acc[s].x += __shfl_xor(acc[s].x, m, 64);
            acc[s].y += __shfl_xor(acc[s].y, m, 64);
            acc[s].z += __shfl_xor(acc[s].z, m, 64);
            acc[s].w += __shfl_xor(acc[s].w, m, 64);
        }
    if (dg == 0) {
#pragma unroll
        for (int s = 0; s < SS; s++)
            *(float4*)&pl1[wave][s][jq * 4] = acc[s];
    }

    // prefetch layer-2 chunks 0..2 BEFORE the barriers (they ride through).
    const float* w2w = w2 + wave * 256;
    stageL2(w2w, 0, wq + 0 * 1024, lane);
    stageL2(w2w, 1, wq + 1 * 1024, lane);
    stageL2(w2w, 2, wq + 2 * 1024, lane);

    WAITLG0;
    __builtin_amdgcn_s_barrier();          // pl1 visible
    if (tid < 32 * SS) {
        int s2 = tid >> 5, j2 = tid & 31;
        float sum = pl1[0][s2][j2] + pl1[1][s2][j2] + pl1[2][s2][j2] +
                    pl1[3][s2][j2] + b1v;
        hs[s2][j2] = fmaxf(sum, 0.f);
    }
    WAITLG0;
    __builtin_amdgcn_s_barrier();          // hs visible

    float4 o[SS];
#pragma unroll
    for (int s = 0; s < SS; s++) o[s] = make_float4(0.f, 0.f, 0.f, 0.f);

    // ---- layer 2 pipeline ----
    WAITV8; l2c<SS>(wq + 0 * 1024, hs, 0, lane, o); stageL2(w2w, 3, wq + 0 * 1024, lane);
    WAITV8; l2c<SS>(wq + 1 * 1024, hs, 1, lane, o); stageL2(w2w, 4, wq + 1 * 1024, lane);
    WAITV8; l2c<SS>(wq + 2 * 1024, hs, 2, lane, o); stageL2(w2w, 5, wq + 2 * 1024, lane);
    WAITV8; l2c<SS>(wq + 0 * 1024, hs, 3, lane, o); stageL2(w2w, 6, wq + 0 * 1024, lane);
    WAITV8; l2c<SS>(wq + 1 * 1024, hs, 4, lane, o); stageL2(w2w, 7, wq + 1 * 1024, lane);
    WAITV8; l2c<SS>(wq + 2 * 1024, hs, 5, lane, o);
    WAITV4; l2c<SS>(wq + 0 * 1024, hs, 6, lane, o);
    WAITV0; l2c<SS>(wq + 1 * 1024, hs, 7, lane, o);

    // epilogue
    float4 bv = *(const float4*)(b2 + wave * 256 + lane * 4);
#pragma unroll
    for (int s = 0; s < SS; s++) {
        float4 o4;
        o4.x = o[s].x + bv.x;
        o4.y = o[s].y + bv.y;
        o4.z = o[s].z + bv.z;
        o4.w = o[s].w + bv.w;
        *(float4*)(out + (size_t)sid[s] * OW + wave * 256 + lane * 4) = o4;
    }
}

__global__ __launch_bounds__(256, 2) void mlp_kernel(
    const float* __restrict__ x, const float* __restrict__ w1s,
    const float* __restrict__ b1s, const float* __restrict__ w2s,
    const float* __restrict__ b2s, const int* __restrict__ offsets,
    const int* __restrict__ count, const int* __restrict__ bucket,
    const int* __restrict__ items, const int* __restrict__ nitems,
    float* __restrict__ out)
{
    __shared__ float xs[SMAX * D];         // 16 KB
    __shared__ float wbuf[4 * 3 * 1024];   // 48 KB: 4 waves x 3 x 4 KB
    __shared__ float pl1[4][SMAX][32];     // 2 KB
    __shared__ float hs[SMAX][H];          // 0.5 KB

    if ((int)blockIdx.x >= nitems[0]) return;
    int item  = items[blockIdx.x];
    int l     = item & (N_LEAVES - 1);
    int start = item >> 11;
    int S     = min(SMAX, count[l] - start);
    int base  = offsets[l] + start;
    int tid   = threadIdx.x;

    const float* w1 = w1s + (size_t)l * D * H;
    const float* w2 = w2s + (size_t)l * H * OW;
    const float* b1 = b1s + (size_t)l * H;
    const float* b2 = b2s + (size_t)l * OW;
    float* wq = wbuf + (tid >> 6) * 3 * 1024;

    switch (S) {
        case 1: mlp_item<1>(tid, x, w1, w2, b1, b2, bucket, base, xs, wq, pl1, hs, out); break;
        case 2: mlp_item<2>(tid, x, w1, w2, b1, b2, bucket, base, xs, wq, pl1, hs, out); break;
        case 3: mlp_item<3>(tid, x, w1, w2, b1, b2, bucket, base, xs, wq, pl1, hs, out); break;
        default: mlp_item<4>(tid, x, w1, w2, b1, b2, bucket, base, xs, wq, pl1, hs, out); break;
    }
}

// ---------------------------------------------------------------------------
extern "C" void kernel_launch(void* const* d_in, const int* in_sizes, int n_in,
                              void* d_out, int out_size, void* d_ws, size_t ws_size,
                              hipStream_t stream)
{
    const float* x   = (const float*)d_in[0];
    const float* nw  = (const float*)d_in[1];
    const float* nb  = (const float*)d_in[2];
    const float* w1s = (const float*)d_in[3];
    const float* b1s = (const float*)d_in[4];
    const float* w2s = (const float*)d_in[5];
    const float* b2s = (const float*)d_in[6];
    float* out = (float*)d_out;

    int* leaf    = (int*)d_ws;
    int* rnk     = leaf + B;
    int* count   = rnk + B;
    int* offsets = count + N_LEAVES;
    int* bucket  = offsets + N_LEAVES;
    int* items   = bucket + B;
    int* nitems  = items + MAX_ITEMS;

    hipMemsetAsync(count, 0, N_LEAVES * sizeof(int), stream);
    hipMemsetAsync(nitems, 0, sizeof(int), stream);
    descent_kernel<<<B / 4, 256, 0, stream>>>(x, nw, nb, leaf, rnk, count);
    scan_kernel<<<1, 256, 0, stream>>>(count, offsets);
    scatter_kernel<<<B / 256, 256, 0, stream>>>(leaf, rnk, offsets, bucket);
    build_items_kernel<<<N_LEAVES / 256, 256, 0, stream>>>(count, items, nitems);
    mlp_kernel<<<MAX_ITEMS, 256, 0, stream>>>(x, w1s, b1s, w2s, b2s,
                                              offsets, count, bucket,
                                              items, nitems, out);
}